// Round 6
// baseline (186.441 us; speedup 1.0000x reference)
//
#include <hip/hip_runtime.h>

typedef __attribute__((ext_vector_type(8))) short short8;
typedef __attribute__((ext_vector_type(4))) short shortx4;
typedef __attribute__((ext_vector_type(4))) float floatx4;
typedef __attribute__((ext_vector_type(4))) _Float16 half4;

__device__ __forceinline__ short bf16_short(float f) {
    unsigned u = __builtin_bit_cast(unsigned, f);
    u = (u + 0x7fff + ((u >> 16) & 1)) >> 16;   // RNE, finite values only
    return (short)u;
}

__device__ __forceinline__ float fast_exp2(float x) {
#if __has_builtin(__builtin_amdgcn_exp2f)
    return __builtin_amdgcn_exp2f(x);
#else
    return __expf(x * 0.6931471805599453f);
#endif
}

// ---------------------------------------------------------------------------
// Kernel 1: relayout weights (fp32 -> bf16) for MFMA A-fragments.
// Wt layout: [tap(9)][cog(4)][chunk(16)][co(128)][j(8)]  (ci = chunk*8+j)
// Wot layout: [chunk(16)][co(128)][j(8)]
// ---------------------------------------------------------------------------
__global__ __launch_bounds__(256) void transform_w(
    const float* __restrict__ wi, const float* __restrict__ wq,
    const float* __restrict__ wo, short* __restrict__ Wt, short* __restrict__ Wot)
{
    int idx = blockIdx.x * 256 + threadIdx.x;
    if (idx < 589824) {
        int j  = idx & 7;
        int t1 = idx >> 3;
        int co = t1 & 127;
        int t2 = t1 >> 7;
        int chunk = t2 & 15;
        int t3 = t2 >> 4;
        int cog = t3 & 3;
        int tap = t3 >> 2;
        int ci = chunk * 8 + j;
        float v;
        if (cog == 0) v = wi[(co * 128 + ci) * 9 + tap];
        else          v = wq[((((cog - 1) * 128) + co) * 128 + ci) * 9 + tap];
        Wt[idx] = bf16_short(v);
    } else if (idx < 589824 + 16384) {
        int i2 = idx - 589824;
        int j  = i2 & 7;
        int co = (i2 >> 3) & 127;
        int chunk = i2 >> 10;
        int ci = chunk * 8 + j;
        Wot[i2] = bf16_short(wo[co * 128 + ci]);
    }
}

// ---------------------------------------------------------------------------
// Kernel 2: fused circular 3x3 convs (init 128ch + qkv 384ch) as implicit GEMM.
// Block = (y-row, cog, b). M=128 (co group), N=48 (cols of row y), K=1152.
// cog==0 -> d_out (fp32) channels 0..127 ; cog 1..3 -> qkv ws **f16**.
// q scaled by 0.25*log2(e) so attention can use exp2 directly.
// ---------------------------------------------------------------------------
__global__ __launch_bounds__(256) void conv_main(
    const float* __restrict__ x, const short* __restrict__ Wt,
    float* __restrict__ dout, _Float16* __restrict__ qkv)
{
    const int y   = blockIdx.x;   // 0..47
    const int cog = blockIdx.y;   // 0..3
    const int b   = blockIdx.z;   // 0..3

    __shared__ short Xs[16 * 3 * 48 * 8];   // [(chunk*3+row)*48+col]*8+j
    __shared__ short Ws[16 * 128 * 8];      // [chunk][co][j]

    const int t = threadIdx.x;

    // Stage X rows y-1,y,y+1 (wrapped): 128ci x 3row x 48col, fp32 -> bf16
    {
        const float* xb = x + b * 128 * 2304;
        #pragma unroll 4
        for (int it = 0; it < 36; ++it) {
            int e   = it * 256 + t;          // 0..9215 column pairs
            int ci  = e / 72;
            int r   = e - ci * 72;
            int row = r / 24;
            int cp  = r - row * 24;
            int rowg = y + row - 1;
            rowg = (rowg < 0) ? rowg + 48 : (rowg >= 48 ? rowg - 48 : rowg);
            float2 v = *(const float2*)(xb + (ci * 48 + rowg) * 48 + cp * 2);
            int slot = ((ci >> 3) * 3 + row) * 48 + cp * 2;
            int j = ci & 7;
            Xs[slot * 8 + j]       = bf16_short(v.x);
            Xs[(slot + 1) * 8 + j] = bf16_short(v.y);
        }
    }

    const int wave = t >> 6, lane = t & 63, quad = lane >> 4, l16 = lane & 15;

    floatx4 acc[2][3];
    #pragma unroll
    for (int i = 0; i < 2; ++i)
        #pragma unroll
        for (int jn = 0; jn < 3; ++jn) acc[i][jn] = (floatx4){0.f, 0.f, 0.f, 0.f};

    // prefetch tap 0 W slab into registers
    short8 wreg[8];
    {
        const short8* src = (const short8*)(Wt + (0 * 4 + cog) * 16384);
        #pragma unroll
        for (int i = 0; i < 8; ++i) wreg[i] = src[i * 256 + t];
    }

    for (int tap = 0; tap < 9; ++tap) {
        __syncthreads();   // prev-tap Ws readers done (also covers X staging at tap 0)
        {
            short8* dst = (short8*)Ws;
            #pragma unroll
            for (int i = 0; i < 8; ++i) dst[i * 256 + t] = wreg[i];
        }
        if (tap < 8) {   // prefetch next tap; completes during this tap's MFMAs
            const short8* src = (const short8*)(Wt + ((tap + 1) * 4 + cog) * 16384);
            #pragma unroll
            for (int i = 0; i < 8; ++i) wreg[i] = src[i * 256 + t];
        }
        __syncthreads();

        const int dy = tap / 3, dx = tap % 3;
        int colw[3];
        #pragma unroll
        for (int nt = 0; nt < 3; ++nt) {
            int c = nt * 16 + l16 + dx - 1;
            c = (c < 0) ? c + 48 : (c >= 48 ? c - 48 : c);
            colw[nt] = c;
        }

        #pragma unroll
        for (int kk = 0; kk < 4; ++kk) {
            int chA = kk * 4 + quad;
            short8 a0 = *(const short8*)&Ws[(chA * 128 + wave * 32 + l16) * 8];
            short8 a1 = *(const short8*)&Ws[(chA * 128 + wave * 32 + 16 + l16) * 8];
            #pragma unroll
            for (int nt = 0; nt < 3; ++nt) {
                short8 bf = *(const short8*)&Xs[((chA * 3 + dy) * 48 + colw[nt]) * 8];
                acc[0][nt] = __builtin_amdgcn_mfma_f32_16x16x32_bf16(a0, bf, acc[0][nt], 0, 0, 0);
                acc[1][nt] = __builtin_amdgcn_mfma_f32_16x16x32_bf16(a1, bf, acc[1][nt], 0, 0, 0);
            }
        }
    }

    // Epilogue: C/D layout col=l16 (spatial), row=quad*4+r (co)
    #pragma unroll
    for (int mt = 0; mt < 2; ++mt)
        #pragma unroll
        for (int nt = 0; nt < 3; ++nt)
            #pragma unroll
            for (int r = 0; r < 4; ++r) {
                int col  = nt * 16 + l16;
                int n    = y * 48 + col;
                int co_l = wave * 32 + mt * 16 + quad * 4 + r;
                float v  = acc[mt][nt][r];
                if (cog == 0) {
                    dout[(b * 256 + co_l) * 2304 + n] = v;            // fp32 out
                } else {
                    int c = (cog - 1) * 128 + co_l;
                    if (c < 128) v *= 0.360673762f;   // 0.25 * log2(e)
                    qkv[(b * 384 + c) * 2304 + n] = (_Float16)v;      // f16 ws
                }
            }
}

// ---------------------------------------------------------------------------
// Kernel 3: flash-style attention via K=16 f16 MFMAs, register-only P.
// Key identity of 16x16x16 layouts: C/D row index (quad*4+r) == A/B k index
// (quad*4+j). So S^T = mfma(K,Q) C-frag, after exp2+cvt, IS the B-operand
// (P^T) of O^T = mfma(V^T, P^T). No LDS round trip, barrier-free inner loop.
// K staged in 256-row chunks [m][d] (reg double-buffered). Row sums: each
// lane's 4 P values share n=l16 -> scalar adds + 2 shuffles at the end.
// attnbuf (bf16) layout (b, h, n, d) flat == raw reshape to (b,128,2304).
// ---------------------------------------------------------------------------
__global__ __launch_bounds__(256) void attn_kernel(
    const _Float16* __restrict__ qkv, short* __restrict__ attnbuf)
{
    const int b  = blockIdx.y >> 3, h = blockIdx.y & 7;
    const int n0 = blockIdx.x * 64;
    constexpr int RS = 24;        // row stride (shorts): d 0..15 data, 8B-aligned rows
    constexpr int CHUNK = 256;

    __shared__ short Qs[64 * RS];          // [n][d] f16 bits
    __shared__ short Ks[CHUNK * RS];       // [m][d] f16 bits

    const int t = threadIdx.x;
    const int wave = t >> 6, lane = t & 63, quad = lane >> 4, l16 = lane & 15;

    const _Float16* qb = qkv + (b * 384 + h * 16) * 2304;
    const _Float16* kb = qkv + (b * 384 + 128 + h * 16) * 2304;
    const _Float16* vb = qkv + (b * 384 + 256 + h * 16) * 2304;

    // stage Q tile (transpose d x 64n -> [n][d]); visible after chunk-0 barrier B
    #pragma unroll
    for (int it = 0; it < 2; ++it) {
        int e = it * 256 + t;              // 0..511
        int d = e >> 5, np = e & 31;
        unsigned v = *(const unsigned*)(qb + d * 2304 + n0 + np * 2);
        Qs[(np * 2) * RS + d]     = (short)(v & 0xffff);
        Qs[(np * 2 + 1) * RS + d] = (short)(v >> 16);
    }

    // prefetch K chunk 0 into registers (thread t <-> row t)
    unsigned short kreg[16];
    #pragma unroll
    for (int d = 0; d < 16; ++d)
        kreg[d] = *(const unsigned short*)(kb + d * 2304 + t);

    floatx4 accO = {0.f, 0.f, 0.f, 0.f};
    float lsum = 0.f;

    for (int c = 0; c < 9; ++c) {
        const int m0 = c * CHUNK;
        __syncthreads();   // prev chunk's Ks readers done (chunk 0: Q staging issued)
        {   // commit prefetched K row t: 4x b64 writes, [m][d]
            #pragma unroll
            for (int i = 0; i < 4; ++i) {
                shortx4 w;
                #pragma unroll
                for (int d = 0; d < 4; ++d) w[d] = (short)kreg[i * 4 + d];
                *(shortx4*)&Ks[t * RS + i * 4] = w;
            }
        }
        if (c < 8) {   // prefetch next chunk; completes during this chunk's compute
            #pragma unroll
            for (int d = 0; d < 16; ++d)
                kreg[d] = *(const unsigned short*)(kb + d * 2304 + m0 + CHUNK + t);
        }
        __syncthreads();

        // Q fragment: B[k=d=quad*4+j][n=l16]  (loop-invariant across chunks)
        half4 qf = *(const half4*)&Qs[(wave * 16 + l16) * RS + quad * 4];

        #pragma unroll
        for (int s = 0; s < 16; ++s) {
            // K fragment: A[m=l16][k=d=quad*4+j]
            half4 kf = *(const half4*)&Ks[(s * 16 + l16) * RS + quad * 4];
            floatx4 z = {0.f, 0.f, 0.f, 0.f};
            // S^T tile: D[m=quad*4+r][n=l16]
            floatx4 st = __builtin_amdgcn_mfma_f32_16x16x16f16(kf, qf, z, 0, 0, 0);

            // exp2 (scale pre-folded in conv) -> P^T fragment: B[k=m][n=l16]
            half4 pf;
            #pragma unroll
            for (int r = 0; r < 4; ++r) {
                float p = fast_exp2(st[r]);
                pf[r] = (_Float16)p;
                lsum += p;
            }
            // V^T fragment straight from global: A[d=l16][m=quad*4+j]
            half4 vf = *(const half4*)(vb + l16 * 2304 + m0 + s * 16 + quad * 4);
            // O^T accum: D[d=quad*4+r][n=l16]
            accO = __builtin_amdgcn_mfma_f32_16x16x16f16(vf, pf, accO, 0, 0, 0);
        }
    }

    // full row sum for n=l16: combine the 4 quads' m-slices
    lsum += __shfl_xor(lsum, 16, 64);
    lsum += __shfl_xor(lsum, 32, 64);
    float rinv = 1.0f / lsum;

    shortx4 o;
    #pragma unroll
    for (int r = 0; r < 4; ++r) o[r] = bf16_short(accO[r] * rinv);
    int n = n0 + wave * 16 + l16;
    *(shortx4*)&attnbuf[((b * 8 + h) * 2304 + n) * 16 + quad * 4] = o;
}

// ---------------------------------------------------------------------------
// Kernel 4: 1x1 conv on raw-reshaped attention buffer. M=128, N=32, K=128.
// Writes d_out (fp32) channels 128..255.
// ---------------------------------------------------------------------------
__global__ __launch_bounds__(256) void conv1x1(
    const short* __restrict__ attnbuf, const short* __restrict__ Wot,
    float* __restrict__ dout)
{
    const int b    = blockIdx.y;
    const int col0 = blockIdx.x * 32;
    constexpr int RSA = 136;              // row stride (shorts), 16B-aligned

    __shared__ short Wo[16 * 128 * 8];
    __shared__ short As[32 * RSA];        // [col][ci]

    const int t = threadIdx.x;
    {   // Wo: contiguous copy
        short8* dst = (short8*)Wo;
        const short8* src = (const short8*)Wot;
        #pragma unroll
        for (int it = 0; it < 8; ++it) dst[it * 256 + t] = src[it * 256 + t];
    }
    {   // As: transpose 128ci x 32col -> [col][ci]
        const short* ab = attnbuf + b * 128 * 2304;
        #pragma unroll
        for (int it = 0; it < 8; ++it) {
            int e = it * 256 + t;
            int ci = e >> 4, cp = e & 15;
            unsigned v = *(const unsigned*)(ab + ci * 2304 + col0 + cp * 2);
            As[(cp * 2) * RSA + ci]     = (short)(v & 0xffff);
            As[(cp * 2 + 1) * RSA + ci] = (short)(v >> 16);
        }
    }
    __syncthreads();

    const int wave = t >> 6, lane = t & 63, quad = lane >> 4, l16 = lane & 15;
    floatx4 acc[2][2];
    #pragma unroll
    for (int i = 0; i < 2; ++i)
        #pragma unroll
        for (int j = 0; j < 2; ++j) acc[i][j] = (floatx4){0.f, 0.f, 0.f, 0.f};

    #pragma unroll
    for (int kk = 0; kk < 4; ++kk) {
        int chA = kk * 4 + quad;
        short8 a0 = *(const short8*)&Wo[(chA * 128 + wave * 32 + l16) * 8];
        short8 a1 = *(const short8*)&Wo[(chA * 128 + wave * 32 + 16 + l16) * 8];
        #pragma unroll
        for (int nt = 0; nt < 2; ++nt) {
            short8 bf = *(const short8*)&As[(nt * 16 + l16) * RSA + kk * 32 + quad * 8];
            acc[0][nt] = __builtin_amdgcn_mfma_f32_16x16x32_bf16(a0, bf, acc[0][nt], 0, 0, 0);
            acc[1][nt] = __builtin_amdgcn_mfma_f32_16x16x32_bf16(a1, bf, acc[1][nt], 0, 0, 0);
        }
    }

    #pragma unroll
    for (int mt = 0; mt < 2; ++mt)
        #pragma unroll
        for (int nt = 0; nt < 2; ++nt)
            #pragma unroll
            for (int r = 0; r < 4; ++r) {
                int co  = wave * 32 + mt * 16 + quad * 4 + r;
                int col = col0 + nt * 16 + l16;
                dout[(b * 256 + 128 + co) * 2304 + col] = acc[mt][nt][r];  // fp32 out
            }
}

// ---------------------------------------------------------------------------
extern "C" void kernel_launch(void* const* d_in, const int* in_sizes, int n_in,
                              void* d_out, int out_size, void* d_ws, size_t ws_size,
                              hipStream_t stream)
{
    const float* x  = (const float*)d_in[0];
    const float* wi = (const float*)d_in[1];
    const float* wq = (const float*)d_in[2];
    const float* wo = (const float*)d_in[3];
    float* dout = (float*)d_out;

    char* ws = (char*)d_ws;
    _Float16* qkv  = (_Float16*)(ws);                   // 7,077,888 B (f16)
    short* attnbuf = (short*)(ws + 7077888);            // 2,359,296 B (bf16)
    short* Wt      = (short*)(ws + 7077888 + 2359296);  // 1,179,648 B
    short* Wot     = (short*)(ws + 7077888 + 2359296 + 1179648); // 32,768 B

    transform_w<<<2368, 256, 0, stream>>>(wi, wq, wo, Wt, Wot);
    conv_main<<<dim3(48, 4, 4), 256, 0, stream>>>(x, Wt, dout, qkv);
    attn_kernel<<<dim3(36, 32), 256, 0, stream>>>(qkv, attnbuf);
    conv1x1<<<dim3(72, 4), 256, 0, stream>>>(attnbuf, Wot, dout);
}